// Round 7
// baseline (784.304 us; speedup 1.0000x reference)
//
#include <hip/hip_runtime.h>

// ---------------------------------------------------------------------------
// SAGE_Re GNN forward, R7.
// - GEMM: restructured K-loop. 3-stage shared LDS pipeline, RAW s_barrier
//   (no vmcnt drain) + manual fine-grained s_waitcnt vmcnt(8)/lgkmcnt(0).
//   Each wave waits only its own chunk-k staging loads; chunks k+1,k+2 stay
//   in flight across barriers (the thing __syncthreads cannot express).
// - agg / CSR / prep: unchanged from R6.
// ---------------------------------------------------------------------------

typedef __attribute__((ext_vector_type(8))) short bf16x8;
typedef __attribute__((ext_vector_type(4))) float f32x4;

// s_waitcnt imm: vmcnt[3:0]|[15:14], expcnt[6:4], lgkmcnt[11:8]
#define WAITVM(N) __builtin_amdgcn_s_waitcnt(0x0F70 | ((N) & 0xF) | ((((N) >> 4) & 3) << 14))
#define WAITLGKM0 __builtin_amdgcn_s_waitcnt(0xC07F)

__device__ __forceinline__ float bf2f(unsigned short u) {
    union { unsigned int i; float f; } v; v.i = ((unsigned int)u) << 16; return v.f;
}
__device__ __forceinline__ unsigned short f2bf(float f) {
    union { float f; unsigned int i; } v; v.f = f;
    unsigned int r = (v.i + 0x7fffu + ((v.i >> 16) & 1u)) >> 16;
    return (unsigned short)r;
}

// ---------------- CSR build ----------------

__global__ __launch_bounds__(256) void zero_int_kernel(int* __restrict__ p, int n)
{
    int i = blockIdx.x * 256 + threadIdx.x;
    if (i < n) p[i] = 0;
}

__global__ __launch_bounds__(256) void count_deg_kernel(
    const int* __restrict__ row, int* __restrict__ deg, int E)
{
    int e = blockIdx.x * 256 + threadIdx.x;
    if (e < E) atomicAdd(&deg[row[e]], 1);
}

__global__ __launch_bounds__(1024) void scan_p1_kernel(
    const int* __restrict__ deg, int* __restrict__ rp,
    int* __restrict__ bsum, int n)
{
    __shared__ int wsum[16];
    int t = threadIdx.x, lane = t & 63, w = t >> 6;
    int base = blockIdx.x * 2048;
    int carry = 0;
    #pragma unroll
    for (int half = 0; half < 2; ++half) {
        int i = base + half * 1024 + t;
        int xv = (i < n) ? deg[i] : 0;
        int s = xv;
        #pragma unroll
        for (int off = 1; off < 64; off <<= 1) {
            int v = __shfl_up(s, off, 64);
            if (lane >= off) s += v;
        }
        if (lane == 63) wsum[w] = s;
        __syncthreads();
        if (w == 0 && lane < 16) {
            int ws = wsum[lane];
            #pragma unroll
            for (int off = 1; off < 16; off <<= 1) {
                int v = __shfl_up(ws, off, 64);
                if (lane >= off) ws += v;
            }
            wsum[lane] = ws;
        }
        __syncthreads();
        int wo = (w == 0) ? 0 : wsum[w - 1];
        if (i < n) rp[i + 1] = carry + wo + s;
        carry += wsum[15];
        if (half == 0) __syncthreads();
    }
    if (t == 0) bsum[blockIdx.x] = carry;
}

__global__ __launch_bounds__(64) void scan_p2_kernel(int* __restrict__ bsum, int B)
{
    int lane = threadIdx.x;
    int v = (lane < B) ? bsum[lane] : 0;
    int s = v;
    #pragma unroll
    for (int off = 1; off < 64; off <<= 1) {
        int u = __shfl_up(s, off, 64);
        if (lane >= off) s += u;
    }
    if (lane < B) bsum[lane] = s - v;
}

__global__ __launch_bounds__(1024) void scan_p3_kernel(
    const int* __restrict__ deg, int* __restrict__ rp,
    int* __restrict__ cursor, const int* __restrict__ bsum,
    float* __restrict__ dinv, float* __restrict__ cinv, int n)
{
    int boff = bsum[blockIdx.x];
    int base = blockIdx.x * 2048;
    #pragma unroll
    for (int half = 0; half < 2; ++half) {
        int i = base + half * 1024 + threadIdx.x;
        if (i < n) {
            int d = deg[i];
            int incl = rp[i + 1] + boff;
            rp[i + 1] = incl;
            cursor[i] = incl - d;
            float df = (float)d;
            dinv[i] = (d > 0) ? rsqrtf(df) : 0.0f;
            cinv[i] = 1.0f / fmaxf(df, 1.0f);
        }
    }
    if (blockIdx.x == 0 && threadIdx.x == 0) rp[0] = 0;
}

__global__ __launch_bounds__(256) void fill_csr_kernel(
    const int* __restrict__ row, const int* __restrict__ col,
    int* __restrict__ cursor, int* __restrict__ colS, int E)
{
    int e = blockIdx.x * 256 + threadIdx.x;
    if (e < E) {
        int p = atomicAdd(&cursor[row[e]], 1);
        colS[p] = col[e];
    }
}

// ---------------- prep ----------------

__global__ __launch_bounds__(256) void f32_to_bf16_kernel(
    const float* __restrict__ src, unsigned short* __restrict__ dst, int n4)
{
    int i = blockIdx.x * 256 + threadIdx.x;
    if (i >= n4) return;
    float4 v = ((const float4*)src)[i];
    ushort4 o;
    o.x = f2bf(v.x); o.y = f2bf(v.y); o.z = f2bf(v.z); o.w = f2bf(v.w);
    ((ushort4*)dst)[i] = o;
}

__global__ __launch_bounds__(256) void prep_w_kernel(
    const float* __restrict__ S1, int K1,
    const float* __restrict__ S2, int K2,
    int Nout, int Npad, unsigned short* __restrict__ dst)
{
    int Ktot = K1 + K2;
    int idx = blockIdx.x * 256 + threadIdx.x;
    if (idx >= Npad * Ktot) return;
    int n = idx / Ktot, k = idx - n * Ktot;
    float v = 0.0f;
    if (n < Nout)
        v = (k < K1) ? S1[(size_t)k * Nout + n] : S2[(size_t)(k - K1) * Nout + n];
    dst[idx] = f2bf(v);
}

// ---------------- aggregation: wave per node, multi-edge lanes ----------------

__device__ __forceinline__ void acc8(float* acc, uint4 u, float s) {
    unsigned int xs[4] = {u.x, u.y, u.z, u.w};
    #pragma unroll
    for (int p = 0; p < 4; ++p) {
        union { unsigned int i; float f; } lo, hi;
        lo.i = xs[p] << 16;
        hi.i = xs[p] & 0xffff0000u;
        acc[2 * p]     += s * lo.f;
        acc[2 * p + 1] += s * hi.f;
    }
}

template <int C, bool HAS_ES>
__global__ __launch_bounds__(256) void agg_bf16_kernel(
    const unsigned short* __restrict__ h, int ldh,
    const int* __restrict__ rp, const int* __restrict__ cols,
    const float* __restrict__ escale, const float* __restrict__ nscale,
    unsigned short* __restrict__ out, int ldo, int n)
{
    constexpr int LPE = (C == 256) ? 32 : 16;  // lanes per edge
    constexpr int EPG = 64 / LPE;              // edges per group (2 or 4)
    constexpr int UNR = 4;                     // gathers in flight per lane
    int node = blockIdx.x * 4 + (threadIdx.x >> 6);
    if (node >= n) return;
    int lane = threadIdx.x & 63;
    int grp = lane / LPE, sub = lane % LPE;
    const unsigned short* hc = h + sub * 8;

    int s = rp[node], e = rp[node + 1];
    float acc[8];
    #pragma unroll
    for (int k = 0; k < 8; ++k) acc[k] = 0.0f;

    for (int i = s; i < e; i += UNR * EPG) {
        int cc[UNR]; float sc[UNR]; uint4 uu[UNR];
        #pragma unroll
        for (int u = 0; u < UNR; ++u) {
            int ii = i + u * EPG + grp;
            bool valid = ii < e;
            int c = valid ? cols[ii] : 0;
            cc[u] = c;
            sc[u] = valid ? (HAS_ES ? escale[c] : 1.0f) : 0.0f;
        }
        #pragma unroll
        for (int u = 0; u < UNR; ++u)
            uu[u] = *(const uint4*)(hc + (size_t)cc[u] * ldh);
        #pragma unroll
        for (int u = 0; u < UNR; ++u)
            acc8(acc, uu[u], sc[u]);
    }

    #pragma unroll
    for (int k = 0; k < 8; ++k) {
        if (EPG == 4) acc[k] += __shfl_xor(acc[k], 16, 64);
        acc[k] += __shfl_xor(acc[k], 32, 64);
    }

    if (grp == 0) {
        float ns = nscale[node];
        uint4 o;
        unsigned int* op = (unsigned int*)&o;
        #pragma unroll
        for (int p = 0; p < 4; ++p) {
            unsigned short a = f2bf(acc[2 * p] * ns);
            unsigned short b = f2bf(acc[2 * p + 1] * ns);
            op[p] = (unsigned int)a | ((unsigned int)b << 16);
        }
        *(uint4*)(out + (size_t)node * ldo + sub * 8) = o;
    }
}

// ---------------- bf16 MFMA GEMM: 3-stage pipeline, raw barriers ------------
// Per chunk per wave: 4 global_load_lds (vmcnt +4). WAITVM(8) = wait own
// chunk-kc loads, keep kc+1/kc+2 in flight. Raw s_barrier emits NO vmcnt(0)
// drain (unlike __syncthreads). Second barrier protects stage overwrite.

__device__ __forceinline__ void g2l16(const unsigned short* g, unsigned short* l) {
    __builtin_amdgcn_global_load_lds(
        (const __attribute__((address_space(1))) unsigned int*)g,
        (__attribute__((address_space(3))) unsigned int*)l, 16, 0, 0);
}

template <int EPI, bool RES_BF16, bool WF32, bool WB16>
__global__ __launch_bounds__(256) void mfma_gemm_kernel(
    const unsigned short* __restrict__ A1, int K1, int lda1,
    const unsigned short* __restrict__ A2, int K2, int lda2,
    const unsigned short* __restrict__ Bt,
    const float* __restrict__ bias,
    const void* __restrict__ res, int ldres,
    const float* __restrict__ alpha_ptr, int alpha_idx,
    float* __restrict__ outf, unsigned short* __restrict__ outb, int ldo,
    int M, int Nout)
{
    __shared__ unsigned short As[3][128 * 32];   // 3 stages x 8 KB
    __shared__ unsigned short Bs[3][128 * 32];   // 3 stages x 8 KB  (48 KB total)
    int t = threadIdx.x;
    int m0 = blockIdx.x * 128, n0 = blockIdx.y * 128;
    int Ktot = K1 + K2;
    int w = t >> 6, lane = t & 63;
    int wm = w & 1, wn = w >> 1;
    int q = lane >> 4, l16 = lane & 15;

    int roff = t >> 2;            // 0..63
    int koff = (t & 3) * 8;       // k offset (shorts)

    int gmA0 = m0 + roff;       if (gmA0 >= M) gmA0 = M - 1;
    int gmA1 = m0 + 64 + roff;  if (gmA1 >= M) gmA1 = M - 1;
    int gnB0 = n0 + roff;
    int gnB1 = n0 + 64 + roff;
    const size_t a0off = (size_t)gmA0, a1off = (size_t)gmA1;

    f32x4 acc[4][4];
    #pragma unroll
    for (int i = 0; i < 4; ++i)
        #pragma unroll
        for (int j = 0; j < 4; ++j)
            #pragma unroll
            for (int r = 0; r < 4; ++r) acc[i][j][r] = 0.0f;

    const int KC = Ktot >> 5;

    auto issue = [&](int kc, int s) {
        int k0 = kc * 32;
        const unsigned short* Ap; int lda, kk;
        if (k0 < K1) { Ap = A1; lda = lda1; kk = k0; }
        else         { Ap = A2; lda = lda2; kk = k0 - K1; }
        g2l16(Ap + a0off * lda + kk + koff, &As[s][w * 512]);
        g2l16(Ap + a1off * lda + kk + koff, &As[s][2048 + w * 512]);
        g2l16(Bt + (size_t)gnB0 * Ktot + k0 + koff, &Bs[s][w * 512]);
        g2l16(Bt + (size_t)gnB1 * Ktot + k0 + koff, &Bs[s][2048 + w * 512]);
    };

    issue(0, 0);
    issue(1, 1);
    issue(2, 2);

    for (int kc = 0; kc < KC; ++kc) {
        int s = kc % 3;
        WAITVM(8);                       // own chunk-kc loads landed; kc+1,kc+2 in flight
        __builtin_amdgcn_s_barrier();    // all waves' chunk-kc data visible
        bf16x8 af[4], bfv[4];
        #pragma unroll
        for (int i = 0; i < 4; ++i)
            af[i] = *(const bf16x8*)&As[s][(wm * 64 + i * 16 + l16) * 32 + q * 8];
        #pragma unroll
        for (int j = 0; j < 4; ++j)
            bfv[j] = *(const bf16x8*)&Bs[s][(wn * 64 + j * 16 + l16) * 32 + q * 8];
        WAITLGKM0;                       // frags in regs
        __builtin_amdgcn_s_barrier();    // all waves done reading stage s
        int nk = kc + 3 < KC ? kc + 3 : KC - 1;   // clamp keeps vmcnt counts uniform
        issue(nk, s);
        #pragma unroll
        for (int i = 0; i < 4; ++i)
            #pragma unroll
            for (int j = 0; j < 4; ++j)
                acc[i][j] = __builtin_amdgcn_mfma_f32_16x16x32_bf16(
                    af[i], bfv[j], acc[i][j], 0, 0, 0);
    }
    WAITVM(0);                           // drain trailing clamped issues

    float alpha = 0.0f;
    if (EPI == 2) alpha = alpha_ptr[alpha_idx];
    #pragma unroll
    for (int i = 0; i < 4; ++i) {
        #pragma unroll
        for (int j = 0; j < 4; ++j) {
            int n = n0 + wn * 64 + j * 16 + l16;
            if (n >= Nout) continue;
            float bv = bias[n];
            #pragma unroll
            for (int r = 0; r < 4; ++r) {
                int m = m0 + wm * 64 + i * 16 + q * 4 + r;
                if (m >= M) continue;
                float v = acc[i][j][r] + bv;
                if (EPI == 1) v = fmaxf(v, 0.0f);
                if (EPI == 2) {
                    float r0 = RES_BF16
                        ? bf2f(((const unsigned short*)res)[(size_t)m * ldres + n])
                        : ((const float*)res)[(size_t)m * ldres + n];
                    v = r0 + alpha * v;
                }
                if (WF32) outf[(size_t)m * ldo + n] = v;
                if (WB16) outb[(size_t)m * ldo + n] = f2bf(v);
            }
        }
    }
}

// ---------------------------------------------------------------------------

extern "C" void kernel_launch(void* const* d_in, const int* in_sizes, int n_in,
                              void* d_out, int out_size, void* d_ws, size_t ws_size,
                              hipStream_t stream)
{
    const float* x      = (const float*)d_in[0];
    const int*   ei     = (const int*)d_in[1];
    const float* alpha  = (const float*)d_in[2];
    const float* W0     = (const float*)d_in[3];
    const float* b0     = (const float*)d_in[4];
    const float* W1     = (const float*)d_in[5];
    const float* R1     = (const float*)d_in[6];
    const float* b1     = (const float*)d_in[7];
    const float* W2     = (const float*)d_in[8];
    const float* R2     = (const float*)d_in[9];
    const float* b2     = (const float*)d_in[10];
    const float* W3     = (const float*)d_in[11];
    const float* b3     = (const float*)d_in[12];
    const float* W4     = (const float*)d_in[13];
    const float* R4     = (const float*)d_in[14];
    const float* b4     = (const float*)d_in[15];

    const int N = in_sizes[0] / 128;
    const int E = in_sizes[1] / 2;
    const int* row = ei;
    const int* col = ei + E;

    size_t off = 0;
    auto alloc = [&](size_t bytes) -> void* {
        void* p = (char*)d_ws + off;
        off += (bytes + 255) & ~(size_t)255;
        return p;
    };
    int*   deg    = (int*)alloc((size_t)N * 4);
    int*   rp     = (int*)alloc((size_t)(N + 1) * 4);
    int*   cursor = (int*)alloc((size_t)N * 4);
    int*   colS   = (int*)alloc((size_t)E * 4);
    int*   bsum   = (int*)alloc((size_t)64 * 4);
    float* dinv   = (float*)alloc((size_t)N * 4);
    float* cinv   = (float*)alloc((size_t)N * 4);
    unsigned short* Wt0 = (unsigned short*)alloc((size_t)128 * 128 * 2);
    unsigned short* Wt1 = (unsigned short*)alloc((size_t)256 * 256 * 2);
    unsigned short* Wt2 = (unsigned short*)alloc((size_t)256 * 512 * 2);
    unsigned short* Wt3 = (unsigned short*)alloc((size_t)256 * 256 * 2);
    unsigned short* Wt4 = (unsigned short*)alloc((size_t)128 * 512 * 2);
    unsigned short* Xb  = (unsigned short*)alloc((size_t)N * 128 * 2);
    unsigned short* Gb  = (unsigned short*)alloc((size_t)N * 256 * 2);
    unsigned short* Pb  = (unsigned short*)alloc((size_t)N * 256 * 2);
    unsigned short* Ab  = (unsigned short*)alloc((size_t)N * 256 * 2);
    unsigned short* Hb  = Xb;  // alias: Xb only read by L0 agg before Hb written
    (void)ws_size;

    // ---- CSR build ----
    const int SB = (N + 2047) / 2048;
    zero_int_kernel<<<(N + 255) / 256, 256, 0, stream>>>(deg, N);
    count_deg_kernel<<<(E + 255) / 256, 256, 0, stream>>>(row, deg, E);
    scan_p1_kernel<<<SB, 1024, 0, stream>>>(deg, rp, bsum, N);
    scan_p2_kernel<<<1, 64, 0, stream>>>(bsum, SB);
    scan_p3_kernel<<<SB, 1024, 0, stream>>>(deg, rp, cursor, bsum, dinv, cinv, N);
    fill_csr_kernel<<<(E + 255) / 256, 256, 0, stream>>>(row, col, cursor, colS, E);

    // ---- prep ----
    f32_to_bf16_kernel<<<(N * 32 + 255) / 256, 256, 0, stream>>>(x, Xb, N * 32);
    prep_w_kernel<<<(128 * 128 + 255) / 256, 256, 0, stream>>>(W0, 128, nullptr, 0, 128, 128, Wt0);
    prep_w_kernel<<<(256 * 256 + 255) / 256, 256, 0, stream>>>(W1, 128, R1, 128, 256, 256, Wt1);
    prep_w_kernel<<<(256 * 512 + 255) / 256, 256, 0, stream>>>(W2, 256, R2, 256, 256, 256, Wt2);
    prep_w_kernel<<<(256 * 256 + 255) / 256, 256, 0, stream>>>(W3, 256, nullptr, 0, 256, 256, Wt3);
    prep_w_kernel<<<(128 * 512 + 255) / 256, 256, 0, stream>>>(W4, 256, R4, 256, 112, 128, Wt4);

    dim3 aggGrid((N + 3) / 4);
    dim3 g1((N + 127) / 128, 1), g2((N + 127) / 128, 2);

    // ---- L0 (GCN): Hb = bf16( x + a0*(gcn_agg(x)@W0 + b0) ) ----
    agg_bf16_kernel<128, true><<<aggGrid, 256, 0, stream>>>(Xb, 128, rp, colS, dinv, dinv, Ab, 128, N);
    mfma_gemm_kernel<2, false, false, true><<<g1, 256, 0, stream>>>(
        Ab, 128, 128, nullptr, 0, 0, Wt0, b0, x, 128, alpha, 0,
        nullptr, Hb, 128, N, 128);

    // ---- L1 (SAGE 128->256): Gb = relu([mean(Hb)|Hb]@[W1;R1]+b1) ----
    agg_bf16_kernel<128, false><<<aggGrid, 256, 0, stream>>>(Hb, 128, rp, colS, nullptr, cinv, Ab, 128, N);
    mfma_gemm_kernel<1, false, false, true><<<g2, 256, 0, stream>>>(
        Ab, 128, 128, Hb, 128, 128, Wt1, b1, nullptr, 0, nullptr, 0,
        nullptr, Gb, 256, N, 256);

    // ---- L2 (SAGE 256->256): Pb = relu([mean(Gb)|Gb]@[W2;R2]+b2) ----
    agg_bf16_kernel<256, false><<<aggGrid, 256, 0, stream>>>(Gb, 256, rp, colS, nullptr, cinv, Ab, 256, N);
    mfma_gemm_kernel<1, false, false, true><<<g2, 256, 0, stream>>>(
        Ab, 256, 256, Gb, 256, 256, Wt2, b2, nullptr, 0, nullptr, 0,
        nullptr, Pb, 256, N, 256);

    // ---- L3 (GCN): Gb = Pb + a3*(gcn_agg(Pb)@W3 + b3) ----
    agg_bf16_kernel<256, true><<<aggGrid, 256, 0, stream>>>(Pb, 256, rp, colS, dinv, dinv, Ab, 256, N);
    mfma_gemm_kernel<2, true, false, true><<<g2, 256, 0, stream>>>(
        Ab, 256, 256, nullptr, 0, 0, Wt3, b3, Pb, 256, alpha, 3,
        nullptr, Gb, 256, N, 256);

    // ---- L4 (SAGE 256->112): d_out = [mean(Gb)|Gb]@[W4;R4]+b4 (fp32) ----
    agg_bf16_kernel<256, false><<<aggGrid, 256, 0, stream>>>(Gb, 256, rp, colS, nullptr, cinv, Ab, 256, N);
    mfma_gemm_kernel<0, false, true, false><<<g1, 256, 0, stream>>>(
        Ab, 256, 256, Gb, 256, 256, Wt4, b4, nullptr, 0, nullptr, 0,
        (float*)d_out, nullptr, 112, N, 112);
}